// Round 12
// baseline (87.047 us; speedup 1.0000x reference)
//
#include <hip/hip_runtime.h>
#include <hip/hip_bf16.h>
#include <math.h>

#define B_ROWS 4096
#define N_ROWS 8192
#define D 128
#define SQRT_SCALE 1.6986436f           // sqrt(2/T*log2(e)); A*B => log2-unit logits
#define LN2F 0.6931471805599453f
#define NT 32            // 32 row-tiles of 256
#define NPAIR 528        // NT*(NT+1)/2 upper-triangular tile pairs
#define NBLK 1056        // 2 blocks (column halves) per pair; 1056 % 8 == 0
#define NSLOT 64         // partials slots per row (ragged; pre-zeroed)
#define TS 256           // tile size (rows)

#define AS1 __attribute__((address_space(1)))
#define AS3 __attribute__((address_space(3)))

typedef __attribute__((ext_vector_type(8))) short bf16x8;
typedef __attribute__((ext_vector_type(4))) float f32x4;

#define MFMA(A, B, C) __builtin_amdgcn_mfma_f32_16x16x32_bf16(A, B, C, 0, 0, 0)

// ---------------- Kernel 1: L2-normalize rows -> bf16 Z = sqrt(2.885)*zhat -----
// Also pre-zeroes partials (64 ragged slots x 8192 rows = 2MB: exactly one f32
// per thread of this 2048x256 grid) and the reduce sync counter.
__global__ __launch_bounds__(256) void normalize_kernel(
    const float* __restrict__ z_i, const float* __restrict__ z_j,
    ushort* __restrict__ Z, float* __restrict__ partials,
    unsigned int* __restrict__ sync_cnt) {
  partials[(size_t)blockIdx.x * 256 + threadIdx.x] = 0.f;  // 2MB pre-zero
  if (blockIdx.x == 0 && threadIdx.x == 0) sync_cnt[0] = 0u;
  const int wave = threadIdx.x >> 6;
  const int lane = threadIdx.x & 63;
  const int row = blockIdx.x * 4 + wave;
  const float* src = (row < B_ROWS) ? (z_i + (size_t)row * D)
                                    : (z_j + (size_t)(row - B_ROWS) * D);
  float2 v = *(const float2*)(src + lane * 2);
  float ss = v.x * v.x + v.y * v.y;
#pragma unroll
  for (int off = 32; off > 0; off >>= 1) ss += __shfl_xor(ss, off);
  float scale = SQRT_SCALE / fmaxf(sqrtf(ss), 1e-12f);
  __hip_bfloat16 g0 = __float2bfloat16(v.x * scale);
  __hip_bfloat16 g1 = __float2bfloat16(v.y * scale);
  ushort2 os;
  os.x = *(ushort*)&g0; os.y = *(ushort*)&g1;
  *(ushort2*)(Z + (size_t)row * D + lane * 2) = os;
}

// ---------------- Kernel 2: symmetric MFMA exp2-rowsum, column-split blocks ----
// One block per (pair p, half h): 256 A-rows (stripe I, direct loads) x 128
// B-cols (rows rJ+h*128.., staged once to 32KB LDS via global_load_lds with
// pre-XOR'd source; conflict-free swizzled ds_read_b128 -- r3/r10 verified).
// LDS 36KB => 4 blocks/CU = 32 waves/CU (vs r10's 16): double latency hiding,
// and the 1056-block grid shrinks the straggler tail to ~T_tile/2.
// Slot map (write-once, no atomics, stripe T): row-sums from (T,J',h) at slot
// 2J'+h (range [2T,63]); col-sums from (K,T,h(row)) at slot K (range [0,T-1]);
// gap [T,2T-1] pre-zeroed by normalize. DIAG pairs skip col-sums.
__global__ __launch_bounds__(512) void sim_kernel(
    const ushort* __restrict__ Z, float* __restrict__ partials,
    float* __restrict__ pos_buf) {
  __shared__ ushort ldsB[128 * 128];   // 32 KB: half-stripe J (128 rows x 256B)
  __shared__ float colpart[8][128];    // 4 KB per-wave col partials

  // XCD-aware bijective swizzle (NBLK % 8 == 0)
  int idx = (int)(blockIdx.x % 8) * (NBLK / 8) + (int)(blockIdx.x / 8);
  const int h = idx & 1;       // column half of the pair
  int p = idx >> 1;            // triangular pair index
  // decode upper-triangular pair: base(I) = I*NT - I*(I-1)/2
  int I = (int)(32.5f - sqrtf(32.5f * 32.5f - 2.0f * (float)p));
  if (I < 0) I = 0;
  if (I > NT - 1) I = NT - 1;
  while ((I + 1) * NT - ((I + 1) * I) / 2 <= p) ++I;
  while (I * NT - (I * (I - 1)) / 2 > p) --I;
  const int J = I + (p - (I * NT - (I * (I - 1)) / 2));
  const int rI = I * TS, rJ = J * TS;
  const int colbase = h * 128;     // tile-local col offset of this block
  const bool DIAG = (I == J);
  const bool POS = (J == I + 16);  // gi^gj == B_ROWS: 4096/256 = 16 tiles apart

  const int t = threadIdx.x;
  const int lane = t & 63;
  const int w = t >> 6;      // 0..7
  const int l15 = lane & 15;
  const int l4 = lane >> 4;  // 0..3

  // ---- Issue A loads FIRST (latency hides under B staging + barrier) ----
  const ushort* Abase = Z + (size_t)(rI + w * 32 + l15) * D + l4 * 8;
  const bf16x8 a00 = *(const bf16x8*)(Abase);
  const bf16x8 a01 = *(const bf16x8*)(Abase + 32);
  const bf16x8 a02 = *(const bf16x8*)(Abase + 64);
  const bf16x8 a03 = *(const bf16x8*)(Abase + 96);
  const bf16x8 a10 = *(const bf16x8*)(Abase + 16 * D);
  const bf16x8 a11 = *(const bf16x8*)(Abase + 16 * D + 32);
  const bf16x8 a12 = *(const bf16x8*)(Abase + 16 * D + 64);
  const bf16x8 a13 = *(const bf16x8*)(Abase + 16 * D + 96);

  // ---- Stage half-stripe J (128 rows) into LDS: 4 rounds x (8 waves x 1KB) ----
  {
    const int rsub = lane >> 4;  // 0..3 row within this wave's 4-row group
#pragma unroll
    for (int i = 0; i < 4; ++i) {
      const int row = i * 32 + w * 4 + rsub;               // 0..127
      const int srcoff = ((lane & 15) * 16) ^ ((row & 7) << 4);
      const char* src =
          (const char*)Z + (size_t)(rJ + colbase + row) * 256 + srcoff;
      char* dst = (char*)ldsB + (size_t)(i * 32 + w * 4) * 256;  // uniform/wave
      __builtin_amdgcn_global_load_lds((AS1 const unsigned int*)src,
                                       (AS3 unsigned int*)dst, 16, 0, 0);
    }
  }
  __syncthreads();  // vmcnt(0) drain before use

  f32x4 rsum0 = {0.f, 0.f, 0.f, 0.f};
  f32x4 rsum1 = {0.f, 0.f, 0.f, 0.f};

#pragma unroll 4
  for (int cs = 0; cs < 8; ++cs) {
    const int br = cs * 16 + l15;          // LDS row 0..127
    const int bo = br * 256, bsw = (br & 7) << 4;
    bf16x8 b0 = *(const bf16x8*)((const char*)ldsB + bo + ((0 + l4 * 16) ^ bsw));
    bf16x8 b1 = *(const bf16x8*)((const char*)ldsB + bo + ((64 + l4 * 16) ^ bsw));
    bf16x8 b2 = *(const bf16x8*)((const char*)ldsB + bo + ((128 + l4 * 16) ^ bsw));
    bf16x8 b3 = *(const bf16x8*)((const char*)ldsB + bo + ((192 + l4 * 16) ^ bsw));
    f32x4 c0 = {0.f, 0.f, 0.f, 0.f};
    f32x4 c1 = {0.f, 0.f, 0.f, 0.f};
    c0 = MFMA(a00, b0, c0); c1 = MFMA(a10, b0, c1);
    c0 = MFMA(a01, b1, c0); c1 = MFMA(a11, b1, c1);
    c0 = MFMA(a02, b2, c0); c1 = MFMA(a12, b2, c1);
    c0 = MFMA(a03, b3, c0); c1 = MFMA(a13, b3, c1);

    const int bt = colbase + cs * 16 + l15;  // tile-local col of this lane
    float cp = 0.f;
    if (!DIAG && !POS) {
      // hot path: bare exp2 + adds
#pragma unroll
      for (int r = 0; r < 4; ++r) {
        float e0 = __builtin_amdgcn_exp2f(c0[r]);
        float e1 = __builtin_amdgcn_exp2f(c1[r]);
        rsum0[r] += e0;
        rsum1[r] += e1;
        cp += e0 + e1;
      }
    } else if (DIAG) {
#pragma unroll
      for (int r = 0; r < 4; ++r) {
        const int at0 = w * 32 + l4 * 4 + r;   // tile-local row (c0)
        const int at1 = at0 + 16;              // (c1)
        float e0 = __builtin_amdgcn_exp2f(c0[r]);
        float e1 = __builtin_amdgcn_exp2f(c1[r]);
        rsum0[r] += (at0 != bt) ? e0 : 0.f;    // exact diagonal mask
        rsum1[r] += (at1 != bt) ? e1 : 0.f;
        // diagonal pair contributes row-sums only (computed in full)
      }
    } else {  // POS pair (J == I+16): tile diagonal holds the positive pairs
#pragma unroll
      for (int r = 0; r < 4; ++r) {
        const int at0 = w * 32 + l4 * 4 + r;
        const int at1 = at0 + 16;
        float e0 = __builtin_amdgcn_exp2f(c0[r]);
        float e1 = __builtin_amdgcn_exp2f(c1[r]);
        if (at0 == bt) { pos_buf[rI + at0] = c0[r]; pos_buf[rJ + at0] = c0[r]; }
        if (at1 == bt) { pos_buf[rI + at1] = c1[r]; pos_buf[rJ + at1] = c1[r]; }
        rsum0[r] += e0;
        rsum1[r] += e1;
        cp += e0 + e1;
      }
    }
    cp += __shfl_xor(cp, 16);
    cp += __shfl_xor(cp, 32);
    if (l4 == 0) colpart[w][cs * 16 + l15] = cp;
  }

  // Row sums (complete over this block's 128 cols): butterfly across 16 lanes,
  // store to slot 2J+h.
#pragma unroll
  for (int r = 0; r < 4; ++r) {
    float v0 = rsum0[r], v1 = rsum1[r];
    v0 += __shfl_xor(v0, 1); v0 += __shfl_xor(v0, 2);
    v0 += __shfl_xor(v0, 4); v0 += __shfl_xor(v0, 8);
    v1 += __shfl_xor(v1, 1); v1 += __shfl_xor(v1, 2);
    v1 += __shfl_xor(v1, 4); v1 += __shfl_xor(v1, 8);
    rsum0[r] = v0; rsum1[r] = v1;
  }
  if (l15 == 0) {
    float* dst = &partials[(size_t)(2 * J + h) * N_ROWS + rI + w * 32];
    *(f32x4*)&dst[l4 * 4] = rsum0;
    *(f32x4*)&dst[16 + l4 * 4] = rsum1;
  }

  // Col sums (symmetry credit to stripe J rows [colbase,+128)): slot I.
  __syncthreads();
  if (!DIAG && t < 128) {
    float v = colpart[0][t] + colpart[1][t] + colpart[2][t] + colpart[3][t] +
              colpart[4][t] + colpart[5][t] + colpart[6][t] + colpart[7][t];
    partials[(size_t)I * N_ROWS + rJ + colbase + t] = v;
  }
}

// ---------------- Kernel 3: per-row term + fused final reduction ----------------
// log2 units: term_ln = (log2(sum) - pos_log2) * ln2. Last block finishes.
__global__ __launch_bounds__(256) void reduce1_kernel(
    const float* __restrict__ partials, const float* __restrict__ pos_buf,
    float* __restrict__ loss_part, unsigned int* __restrict__ sync_cnt,
    float* __restrict__ out) {
  const int row = blockIdx.x * 256 + threadIdx.x;
  float tot = 0.f;
#pragma unroll 8
  for (int s = 0; s < NSLOT; ++s) tot += partials[(size_t)s * N_ROWS + row];
  float term = (log2f(tot) - pos_buf[row]) * LN2F;
#pragma unroll
  for (int off = 32; off > 0; off >>= 1) term += __shfl_xor(term, off);
  __shared__ float wsum[4];
  __shared__ unsigned int is_last;
  if ((threadIdx.x & 63) == 0) wsum[threadIdx.x >> 6] = term;
  __syncthreads();
  if (threadIdx.x == 0) {
    float bsum = wsum[0] + wsum[1] + wsum[2] + wsum[3];
    __hip_atomic_store(&loss_part[blockIdx.x], bsum, __ATOMIC_RELEASE,
                       __HIP_MEMORY_SCOPE_AGENT);
    unsigned int old = __hip_atomic_fetch_add(sync_cnt, 1u, __ATOMIC_ACQ_REL,
                                              __HIP_MEMORY_SCOPE_AGENT);
    is_last = (old == (N_ROWS / 256) - 1) ? 1u : 0u;
  }
  __syncthreads();
  if (is_last && threadIdx.x < 64) {
    float v = (threadIdx.x < 32)
                  ? __hip_atomic_load(&loss_part[threadIdx.x], __ATOMIC_ACQUIRE,
                                      __HIP_MEMORY_SCOPE_AGENT)
                  : 0.f;
#pragma unroll
    for (int off = 32; off > 0; off >>= 1) v += __shfl_xor(v, off);
    if (threadIdx.x == 0) out[0] = v / (float)N_ROWS;
  }
}

extern "C" void kernel_launch(void* const* d_in, const int* in_sizes, int n_in,
                              void* d_out, int out_size, void* d_ws, size_t ws_size,
                              hipStream_t stream) {
  const float* z_i = (const float*)d_in[0];
  const float* z_j = (const float*)d_in[1];
  float* out = (float*)d_out;

  ushort* Z = (ushort*)d_ws;                                        // 2 MB
  float* partials = (float*)(Z + (size_t)N_ROWS * D);               // 2 MB
  float* pos_buf = partials + (size_t)NSLOT * N_ROWS;               // 32 KB
  float* loss_part = pos_buf + N_ROWS;                              // 128 B
  unsigned int* sync_cnt = (unsigned int*)(loss_part + 32);         // 4 B

  hipLaunchKernelGGL(normalize_kernel, dim3(N_ROWS / 4), dim3(256), 0, stream,
                     z_i, z_j, Z, partials, sync_cnt);
  hipLaunchKernelGGL(sim_kernel, dim3(NBLK), dim3(512), 0, stream, Z, partials,
                     pos_buf);
  hipLaunchKernelGGL(reduce1_kernel, dim3(N_ROWS / 256), dim3(256), 0, stream,
                     partials, pos_buf, loss_part, sync_cnt, out);
}

// Round 14
// 86.084 us; speedup vs baseline: 1.0112x; 1.0112x over previous
//
#include <hip/hip_runtime.h>
#include <hip/hip_bf16.h>
#include <math.h>

#define B_ROWS 4096
#define N_ROWS 8192
#define D 128
#define SQRT_SCALE 1.6986436f           // sqrt(2/T*log2(e)); A*B => log2-unit logits
#define LN2F 0.6931471805599453f
#define NT 32            // 32 row-tiles of 256
#define NBLK 528         // NT*(NT+1)/2 upper-triangular tile pairs (528%8==0)
#define NSLOT 32         // contribution slots per row (one per tile pair)
#define TS 256           // tile size

#define AS1 __attribute__((address_space(1)))
#define AS3 __attribute__((address_space(3)))

typedef __attribute__((ext_vector_type(8))) short bf16x8;
typedef __attribute__((ext_vector_type(4))) float f32x4;

#define MFMA(A, B, C) __builtin_amdgcn_mfma_f32_16x16x32_bf16(A, B, C, 0, 0, 0)

// ---------------- Kernel 1: L2-normalize rows -> bf16 Z = sqrt(2.885)*zhat -----
__global__ __launch_bounds__(256) void normalize_kernel(
    const float* __restrict__ z_i, const float* __restrict__ z_j,
    ushort* __restrict__ Z, unsigned int* __restrict__ sync_cnt) {
  if (blockIdx.x == 0 && threadIdx.x == 0) sync_cnt[0] = 0u;
  const int wave = threadIdx.x >> 6;
  const int lane = threadIdx.x & 63;
  const int row = blockIdx.x * 4 + wave;
  const float* src = (row < B_ROWS) ? (z_i + (size_t)row * D)
                                    : (z_j + (size_t)(row - B_ROWS) * D);
  float2 v = *(const float2*)(src + lane * 2);
  float ss = v.x * v.x + v.y * v.y;
#pragma unroll
  for (int off = 32; off > 0; off >>= 1) ss += __shfl_xor(ss, off);
  float scale = SQRT_SCALE / fmaxf(sqrtf(ss), 1e-12f);
  __hip_bfloat16 g0 = __float2bfloat16(v.x * scale);
  __hip_bfloat16 g1 = __float2bfloat16(v.y * scale);
  ushort2 os;
  os.x = *(ushort*)&g0; os.y = *(ushort*)&g1;
  *(ushort2*)(Z + (size_t)row * D + lane * 2) = os;
}

// ---------------- Kernel 2: symmetric MFMA exp2-rowsum, split-stage pipeline ---
// r10/r11 structure (best measured) + 2-phase staging (guide T3-minimum):
// issue stage(half1) BEFORE computing half0 so half1's L3 flight time hides
// under compute, and the prologue drain covers only A + 32KB instead of A+64KB.
// r12 falsified the occupancy theory (32 waves/CU was worse); the limiter is
// the per-block serial memory prologue at ~11 B/cyc/CU effective scatter rate.
// All else unchanged: one block per pair (I,J), J>=I; A direct (48-VGPR fit,
// r9-verified no-spill); B staged via global_load_lds, linear dest +
// pre-XOR'd source, conflict-free swizzled ds_read_b128 (r3-verified);
// write-once partials slots (row-sums at slot J, col-sums at slot I).
__global__ __launch_bounds__(512) void sim_kernel(
    const ushort* __restrict__ Z, float* __restrict__ partials,
    float* __restrict__ pos_buf) {
  __shared__ ushort ldsB[TS * 128];     // 64 KB, stripe J (swizzled content)
  __shared__ float colpart[8][TS];      // 8 KB per-wave col partials

  // XCD-aware bijective swizzle (NBLK % 8 == 0)
  int idx = (int)(blockIdx.x % 8) * (NBLK / 8) + (int)(blockIdx.x / 8);
  // decode upper-triangular pair: base(I) = I*NT - I*(I-1)/2
  int I = (int)(32.5f - sqrtf(32.5f * 32.5f - 2.0f * (float)idx));
  if (I < 0) I = 0;
  if (I > NT - 1) I = NT - 1;
  while ((I + 1) * NT - ((I + 1) * I) / 2 <= idx) ++I;
  while (I * NT - (I * (I - 1)) / 2 > idx) --I;
  const int J = I + (idx - (I * NT - (I * (I - 1)) / 2));
  const int rI = I * TS, rJ = J * TS;
  const bool DIAG = (I == J);
  const bool POS = (J == I + 16);  // gi^gj == B_ROWS: 4096/256 = 16 tiles apart

  const int t = threadIdx.x;
  const int lane = t & 63;
  const int w = t >> 6;      // 0..7
  const int l15 = lane & 15;
  const int l4 = lane >> 4;  // 0..3
  const int rsub = lane >> 4;

  // ---- Phase 0: issue stage(half0: B rows 0..127) + A loads, then drain ----
#pragma unroll
  for (int i = 0; i < 4; ++i) {
    const int row = i * 32 + w * 4 + rsub;                 // 0..127
    const int srcoff = (l15 * 16) ^ ((row & 7) << 4);
    const char* src = (const char*)Z + (size_t)(rJ + row) * 256 + srcoff;
    char* dst = (char*)ldsB + (size_t)(i * 32 + w * 4) * 256;  // uniform/wave
    __builtin_amdgcn_global_load_lds((AS1 const unsigned int*)src,
                                     (AS3 unsigned int*)dst, 16, 0, 0);
  }
  const ushort* Abase = Z + (size_t)(rI + w * 32 + l15) * D + l4 * 8;
  const bf16x8 a00 = *(const bf16x8*)(Abase);
  const bf16x8 a01 = *(const bf16x8*)(Abase + 32);
  const bf16x8 a02 = *(const bf16x8*)(Abase + 64);
  const bf16x8 a03 = *(const bf16x8*)(Abase + 96);
  const bf16x8 a10 = *(const bf16x8*)(Abase + 16 * D);
  const bf16x8 a11 = *(const bf16x8*)(Abase + 16 * D + 32);
  const bf16x8 a12 = *(const bf16x8*)(Abase + 16 * D + 64);
  const bf16x8 a13 = *(const bf16x8*)(Abase + 16 * D + 96);
  __syncthreads();  // drains A + half0 (96 KB, not 128)

  // ---- Issue stage(half1: B rows 128..255); its flight hides under compute ----
#pragma unroll
  for (int i = 4; i < 8; ++i) {
    const int row = i * 32 + w * 4 + rsub;                 // 128..255
    const int srcoff = (l15 * 16) ^ ((row & 7) << 4);
    const char* src = (const char*)Z + (size_t)(rJ + row) * 256 + srcoff;
    char* dst = (char*)ldsB + (size_t)(i * 32 + w * 4) * 256;
    __builtin_amdgcn_global_load_lds((AS1 const unsigned int*)src,
                                     (AS3 unsigned int*)dst, 16, 0, 0);
  }

  f32x4 rsum0 = {0.f, 0.f, 0.f, 0.f};
  f32x4 rsum1 = {0.f, 0.f, 0.f, 0.f};

  // ---- Compute: two halves of 8 col-subtiles; barrier between drains half1 ----
#pragma unroll
  for (int half = 0; half < 2; ++half) {
    if (half == 1) __syncthreads();  // half1 data arrived (drain mostly hidden)
#pragma unroll 4
    for (int csl = 0; csl < 8; ++csl) {
      const int cs = half * 8 + csl;
      const int br = cs * 16 + l15;
      const int bo = br * 256, bsw = (br & 7) << 4;
      bf16x8 b0 = *(const bf16x8*)((const char*)ldsB + bo + ((0 + l4 * 16) ^ bsw));
      bf16x8 b1 = *(const bf16x8*)((const char*)ldsB + bo + ((64 + l4 * 16) ^ bsw));
      bf16x8 b2 = *(const bf16x8*)((const char*)ldsB + bo + ((128 + l4 * 16) ^ bsw));
      bf16x8 b3 = *(const bf16x8*)((const char*)ldsB + bo + ((192 + l4 * 16) ^ bsw));
      f32x4 c0 = {0.f, 0.f, 0.f, 0.f};
      f32x4 c1 = {0.f, 0.f, 0.f, 0.f};
      c0 = MFMA(a00, b0, c0); c1 = MFMA(a10, b0, c1);
      c0 = MFMA(a01, b1, c0); c1 = MFMA(a11, b1, c1);
      c0 = MFMA(a02, b2, c0); c1 = MFMA(a12, b2, c1);
      c0 = MFMA(a03, b3, c0); c1 = MFMA(a13, b3, c1);

      const int bt = cs * 16 + l15;  // tile-local col of this lane
      float cp = 0.f;
      if (!DIAG && !POS) {
        // hot path (480/528 blocks): bare exp2 + adds
#pragma unroll
        for (int r = 0; r < 4; ++r) {
          float e0 = __builtin_amdgcn_exp2f(c0[r]);
          float e1 = __builtin_amdgcn_exp2f(c1[r]);
          rsum0[r] += e0;
          rsum1[r] += e1;
          cp += e0 + e1;
        }
      } else if (DIAG) {
#pragma unroll
        for (int r = 0; r < 4; ++r) {
          const int at0 = w * 32 + l4 * 4 + r;   // tile-local row (c0)
          const int at1 = at0 + 16;              // (c1)
          float e0 = __builtin_amdgcn_exp2f(c0[r]);
          float e1 = __builtin_amdgcn_exp2f(c1[r]);
          rsum0[r] += (at0 != bt) ? e0 : 0.f;    // exact diagonal mask
          rsum1[r] += (at1 != bt) ? e1 : 0.f;
          // diagonal tile contributes row-sums only (computed in full)
        }
      } else {  // POS tile (J == I+16): tile diagonal holds the positive pairs
#pragma unroll
        for (int r = 0; r < 4; ++r) {
          const int at0 = w * 32 + l4 * 4 + r;
          const int at1 = at0 + 16;
          float e0 = __builtin_amdgcn_exp2f(c0[r]);
          float e1 = __builtin_amdgcn_exp2f(c1[r]);
          if (at0 == bt) { pos_buf[rI + at0] = c0[r]; pos_buf[rJ + at0] = c0[r]; }
          if (at1 == bt) { pos_buf[rI + at1] = c1[r]; pos_buf[rJ + at1] = c1[r]; }
          rsum0[r] += e0;
          rsum1[r] += e1;
          cp += e0 + e1;
        }
      }
      cp += __shfl_xor(cp, 16);
      cp += __shfl_xor(cp, 32);
      if (l4 == 0) colpart[w][bt] = cp;
    }
  }

  // Row sums: butterfly across the 16 column-lanes; rows complete (all 256 cols).
#pragma unroll
  for (int r = 0; r < 4; ++r) {
    float v0 = rsum0[r], v1 = rsum1[r];
    v0 += __shfl_xor(v0, 1); v0 += __shfl_xor(v0, 2);
    v0 += __shfl_xor(v0, 4); v0 += __shfl_xor(v0, 8);
    v1 += __shfl_xor(v1, 1); v1 += __shfl_xor(v1, 2);
    v1 += __shfl_xor(v1, 4); v1 += __shfl_xor(v1, 8);
    rsum0[r] = v0; rsum1[r] = v1;
  }
  if (l15 == 0) {
    *(f32x4*)&partials[(size_t)J * N_ROWS + rI + w * 32 + l4 * 4] = rsum0;
    *(f32x4*)&partials[(size_t)J * N_ROWS + rI + w * 32 + 16 + l4 * 4] = rsum1;
  }

  // Col sums (symmetry credit to stripe J): combine 8 wave partials, slot I.
  __syncthreads();
  if (!DIAG && t < TS) {
    float v = colpart[0][t] + colpart[1][t] + colpart[2][t] + colpart[3][t] +
              colpart[4][t] + colpart[5][t] + colpart[6][t] + colpart[7][t];
    partials[(size_t)I * N_ROWS + rJ + t] = v;
  }
}

// ---------------- Kernel 3: per-row term + fused final reduction ----------------
// log2 units: term_ln = (log2(sum) - pos_log2) * ln2. Last block finishes.
__global__ __launch_bounds__(256) void reduce1_kernel(
    const float* __restrict__ partials, const float* __restrict__ pos_buf,
    float* __restrict__ loss_part, unsigned int* __restrict__ sync_cnt,
    float* __restrict__ out) {
  const int row = blockIdx.x * 256 + threadIdx.x;
  float tot = 0.f;
#pragma unroll 8
  for (int s = 0; s < NSLOT; ++s) tot += partials[(size_t)s * N_ROWS + row];
  float term = (log2f(tot) - pos_buf[row]) * LN2F;
#pragma unroll
  for (int off = 32; off > 0; off >>= 1) term += __shfl_xor(term, off);
  __shared__ float wsum[4];
  __shared__ unsigned int is_last;
  if ((threadIdx.x & 63) == 0) wsum[threadIdx.x >> 6] = term;
  __syncthreads();
  if (threadIdx.x == 0) {
    float bsum = wsum[0] + wsum[1] + wsum[2] + wsum[3];
    __hip_atomic_store(&loss_part[blockIdx.x], bsum, __ATOMIC_RELEASE,
                       __HIP_MEMORY_SCOPE_AGENT);
    unsigned int old = __hip_atomic_fetch_add(sync_cnt, 1u, __ATOMIC_ACQ_REL,
                                              __HIP_MEMORY_SCOPE_AGENT);
    is_last = (old == (N_ROWS / 256) - 1) ? 1u : 0u;
  }
  __syncthreads();
  if (is_last && threadIdx.x < 64) {
    float v = (threadIdx.x < 32)
                  ? __hip_atomic_load(&loss_part[threadIdx.x], __ATOMIC_ACQUIRE,
                                      __HIP_MEMORY_SCOPE_AGENT)
                  : 0.f;
#pragma unroll
    for (int off = 32; off > 0; off >>= 1) v += __shfl_xor(v, off);
    if (threadIdx.x == 0) out[0] = v / (float)N_ROWS;
  }
}

extern "C" void kernel_launch(void* const* d_in, const int* in_sizes, int n_in,
                              void* d_out, int out_size, void* d_ws, size_t ws_size,
                              hipStream_t stream) {
  const float* z_i = (const float*)d_in[0];
  const float* z_j = (const float*)d_in[1];
  float* out = (float*)d_out;

  ushort* Z = (ushort*)d_ws;                                        // 2 MB
  float* partials = (float*)(Z + (size_t)N_ROWS * D);               // 1 MB
  float* pos_buf = partials + (size_t)NSLOT * N_ROWS;               // 32 KB
  float* loss_part = pos_buf + N_ROWS;                              // 128 B
  unsigned int* sync_cnt = (unsigned int*)(loss_part + 32);         // 4 B

  hipLaunchKernelGGL(normalize_kernel, dim3(N_ROWS / 4), dim3(256), 0, stream,
                     z_i, z_j, Z, sync_cnt);
  hipLaunchKernelGGL(sim_kernel, dim3(NBLK), dim3(512), 0, stream, Z, partials,
                     pos_buf);
  hipLaunchKernelGGL(reduce1_kernel, dim3(N_ROWS / 256), dim3(256), 0, stream,
                     partials, pos_buf, loss_part, sync_cnt, out);
}

// Round 15
// 83.167 us; speedup vs baseline: 1.0467x; 1.0351x over previous
//
#include <hip/hip_runtime.h>
#include <hip/hip_bf16.h>
#include <math.h>

#define B_ROWS 4096
#define N_ROWS 8192
#define D 128
#define EXP2_SCALE 2.8853900817779268f  // 2/T*log2(e): exp(sim*2) = exp2(sim*EXP2_SCALE)
#define LN2F 0.6931471805599453f
#define NT 32            // 32 row-tiles of 256
#define NBLK 528         // NT*(NT+1)/2 upper-triangular tile pairs (528%8==0)
#define NSLOT 32         // contribution slots per row (one per tile pair)
#define TS 256           // tile size

#define AS1 __attribute__((address_space(1)))
#define AS3 __attribute__((address_space(3)))

typedef __attribute__((ext_vector_type(8))) short bf16x8;
typedef __attribute__((ext_vector_type(4))) float f32x4;

#define MFMA(A, B, C) __builtin_amdgcn_mfma_f32_16x16x32_bf16(A, B, C, 0, 0, 0)

// ---------------- Kernel 1: L2-normalize rows -> bf16 Zu (unit) and Zs (x2.885) --
__global__ __launch_bounds__(256) void normalize_kernel(
    const float* __restrict__ z_i, const float* __restrict__ z_j,
    ushort* __restrict__ Zu, ushort* __restrict__ Zs) {
  const int wave = threadIdx.x >> 6;
  const int lane = threadIdx.x & 63;
  const int row = blockIdx.x * 4 + wave;
  const float* src = (row < B_ROWS) ? (z_i + (size_t)row * D)
                                    : (z_j + (size_t)(row - B_ROWS) * D);
  float2 v = *(const float2*)(src + lane * 2);
  float ss = v.x * v.x + v.y * v.y;
#pragma unroll
  for (int off = 32; off > 0; off >>= 1) ss += __shfl_xor(ss, off);
  float scale = 1.0f / fmaxf(sqrtf(ss), 1e-12f);
  float u0 = v.x * scale, u1 = v.y * scale;
  __hip_bfloat16 h0 = __float2bfloat16(u0);
  __hip_bfloat16 h1 = __float2bfloat16(u1);
  __hip_bfloat16 g0 = __float2bfloat16(u0 * EXP2_SCALE);
  __hip_bfloat16 g1 = __float2bfloat16(u1 * EXP2_SCALE);
  ushort2 ou, os;
  ou.x = *(ushort*)&h0; ou.y = *(ushort*)&h1;
  os.x = *(ushort*)&g0; os.y = *(ushort*)&g1;
  *(ushort2*)(Zu + (size_t)row * D + lane * 2) = ou;
  *(ushort2*)(Zs + (size_t)row * D + lane * 2) = os;
}

// ---------------- Kernel 2: symmetric MFMA exp2-rowsum, 256x256 tiles ----------
// Best-measured structure (r10: 83.4us total). One block per tile-pair (I,J),
// J>=I; NBLK=528. A read direct (64KB/block, no redundancy), B staged once to
// LDS (64KB/block) via global_load_lds: linear dest + pre-XOR'd source; reads
// use the same XOR ((row&7)<<4) => conflict-free ds_read_b128 (r3-verified).
// Wave w owns tile rows [w*32,w*32+32) x all 256 cols => complete row-sums,
// ONE partials slot per tile pair; col-sums (symmetry) combined via 8KB LDS.
// 48 VGPR (r9-verified no-spill). No atomics in the hot path.
__global__ __launch_bounds__(512) void sim_kernel(
    const ushort* __restrict__ Zu, const ushort* __restrict__ Zs,
    float* __restrict__ partials, float* __restrict__ pos_buf) {
  __shared__ ushort ldsB[TS * 128];     // 64 KB, stripe J (swizzled content)
  __shared__ float colpart[8][TS];      // 8 KB per-wave col partials

  // XCD-aware bijective swizzle (NBLK % 8 == 0)
  int idx = (int)(blockIdx.x % 8) * (NBLK / 8) + (int)(blockIdx.x / 8);
  // decode upper-triangular pair: base(I) = I*NT - I*(I-1)/2
  int I = (int)(32.5f - sqrtf(32.5f * 32.5f - 2.0f * (float)idx));
  if (I < 0) I = 0;
  if (I > NT - 1) I = NT - 1;
  while ((I + 1) * NT - ((I + 1) * I) / 2 <= idx) ++I;
  while (I * NT - (I * (I - 1)) / 2 > idx) --I;
  const int J = I + (idx - (I * NT - (I * (I - 1)) / 2));
  const int rI = I * TS, rJ = J * TS;
  const bool DIAG = (I == J);
  const bool POS = (J == I + 16);  // gi^gj == B_ROWS: 4096/256 = 16 tiles apart

  const int t = threadIdx.x;
  const int lane = t & 63;
  const int w = t >> 6;      // 0..7
  const int l15 = lane & 15;
  const int l4 = lane >> 4;  // 0..3

  // ---- Issue A loads FIRST (latency hides under B staging + barrier) ----
  const ushort* Abase = Zu + (size_t)(rI + w * 32 + l15) * D + l4 * 8;
  const bf16x8 a00 = *(const bf16x8*)(Abase);
  const bf16x8 a01 = *(const bf16x8*)(Abase + 32);
  const bf16x8 a02 = *(const bf16x8*)(Abase + 64);
  const bf16x8 a03 = *(const bf16x8*)(Abase + 96);
  const bf16x8 a10 = *(const bf16x8*)(Abase + 16 * D);
  const bf16x8 a11 = *(const bf16x8*)(Abase + 16 * D + 32);
  const bf16x8 a12 = *(const bf16x8*)(Abase + 16 * D + 64);
  const bf16x8 a13 = *(const bf16x8*)(Abase + 16 * D + 96);

  // ---- Stage stripe J into LDS: 8 rounds x (8 waves x 1KB) ----
  // Linear wave-uniform dest; source pre-XOR'd so LDS[row][x] = Z[row][x^sw].
  {
    const int rsub = lane >> 4;  // 0..3 row within this wave's 4-row group
#pragma unroll
    for (int i = 0; i < 8; ++i) {
      const int row = i * 32 + w * 4 + rsub;               // 0..255
      const int srcoff = ((lane & 15) * 16) ^ ((row & 7) << 4);
      const char* src = (const char*)Zs + (size_t)(rJ + row) * 256 + srcoff;
      char* dst = (char*)ldsB + (size_t)(i * 32 + w * 4) * 256;  // uniform/wave
      __builtin_amdgcn_global_load_lds((AS1 const unsigned int*)src,
                                       (AS3 unsigned int*)dst, 16, 0, 0);
    }
  }
  __syncthreads();  // vmcnt(0) drain before use

  f32x4 rsum0 = {0.f, 0.f, 0.f, 0.f};
  f32x4 rsum1 = {0.f, 0.f, 0.f, 0.f};

#pragma unroll 4
  for (int cs = 0; cs < 16; ++cs) {
    // B fragments for cols [cs*16, cs*16+16) from LDS (swizzled read).
    const int br = cs * 16 + l15;
    const int bo = br * 256, bsw = (br & 7) << 4;
    bf16x8 b0 = *(const bf16x8*)((const char*)ldsB + bo + ((0 + l4 * 16) ^ bsw));
    bf16x8 b1 = *(const bf16x8*)((const char*)ldsB + bo + ((64 + l4 * 16) ^ bsw));
    bf16x8 b2 = *(const bf16x8*)((const char*)ldsB + bo + ((128 + l4 * 16) ^ bsw));
    bf16x8 b3 = *(const bf16x8*)((const char*)ldsB + bo + ((192 + l4 * 16) ^ bsw));
    f32x4 c0 = {0.f, 0.f, 0.f, 0.f};
    f32x4 c1 = {0.f, 0.f, 0.f, 0.f};
    c0 = MFMA(a00, b0, c0); c1 = MFMA(a10, b0, c1);
    c0 = MFMA(a01, b1, c0); c1 = MFMA(a11, b1, c1);
    c0 = MFMA(a02, b2, c0); c1 = MFMA(a12, b2, c1);
    c0 = MFMA(a03, b3, c0); c1 = MFMA(a13, b3, c1);

    const int bt = cs * 16 + l15;  // tile-local col of this lane
    float cp = 0.f;
    if (!DIAG && !POS) {
      // hot path (480/528 blocks): bare exp2 + adds
#pragma unroll
      for (int r = 0; r < 4; ++r) {
        float e0 = __builtin_amdgcn_exp2f(c0[r]);
        float e1 = __builtin_amdgcn_exp2f(c1[r]);
        rsum0[r] += e0;
        rsum1[r] += e1;
        cp += e0 + e1;
      }
    } else if (DIAG) {
#pragma unroll
      for (int r = 0; r < 4; ++r) {
        const int at0 = w * 32 + l4 * 4 + r;   // tile-local row (c0)
        const int at1 = at0 + 16;              // (c1)
        float e0 = __builtin_amdgcn_exp2f(c0[r]);
        float e1 = __builtin_amdgcn_exp2f(c1[r]);
        rsum0[r] += (at0 != bt) ? e0 : 0.f;    // exact diagonal mask
        rsum1[r] += (at1 != bt) ? e1 : 0.f;
        // diagonal tile contributes row-sums only (computed in full)
      }
    } else {  // POS tile (J == I+16): tile diagonal holds the positive pairs
#pragma unroll
      for (int r = 0; r < 4; ++r) {
        const int at0 = w * 32 + l4 * 4 + r;
        const int at1 = at0 + 16;
        float e0 = __builtin_amdgcn_exp2f(c0[r]);
        float e1 = __builtin_amdgcn_exp2f(c1[r]);
        if (at0 == bt) { pos_buf[rI + at0] = c0[r]; pos_buf[rJ + at0] = c0[r]; }
        if (at1 == bt) { pos_buf[rI + at1] = c1[r]; pos_buf[rJ + at1] = c1[r]; }
        rsum0[r] += e0;
        rsum1[r] += e1;
        cp += e0 + e1;
      }
    }
    // col partial for this cs: reduce across the 4 row-lane-groups
    cp += __shfl_xor(cp, 16);
    cp += __shfl_xor(cp, 32);
    if (l4 == 0) colpart[w][bt] = cp;
  }

  // Row sums: butterfly across the 16 column-lanes; rows complete (all 256 cols).
#pragma unroll
  for (int r = 0; r < 4; ++r) {
    float v0 = rsum0[r], v1 = rsum1[r];
    v0 += __shfl_xor(v0, 1); v0 += __shfl_xor(v0, 2);
    v0 += __shfl_xor(v0, 4); v0 += __shfl_xor(v0, 8);
    v1 += __shfl_xor(v1, 1); v1 += __shfl_xor(v1, 2);
    v1 += __shfl_xor(v1, 4); v1 += __shfl_xor(v1, 8);
    rsum0[r] = v0; rsum1[r] = v1;
  }
  if (l15 == 0) {  // 4 lanes (l4=0..3) store 2x contiguous 64B lines
    *(f32x4*)&partials[(size_t)J * N_ROWS + rI + w * 32 + l4 * 4] = rsum0;
    *(f32x4*)&partials[(size_t)J * N_ROWS + rI + w * 32 + 16 + l4 * 4] = rsum1;
  }

  // Col sums (symmetry credit to stripe J): combine 8 wave partials, slot I.
  __syncthreads();
  if (!DIAG && t < TS) {
    float v = colpart[0][t] + colpart[1][t] + colpart[2][t] + colpart[3][t] +
              colpart[4][t] + colpart[5][t] + colpart[6][t] + colpart[7][t];
    partials[(size_t)I * N_ROWS + rJ + t] = v;
  }
}

// ---------------- Kernel 3: per-row term + block partial sums ----------------
// Everything is in log2 units: term_ln = (log2(sum) - pos_log2) * ln2.
__global__ __launch_bounds__(256) void reduce1_kernel(
    const float* __restrict__ partials, const float* __restrict__ pos_buf,
    float* __restrict__ loss_part) {
  const int row = blockIdx.x * 256 + threadIdx.x;
  float tot = 0.f;
#pragma unroll 8
  for (int s = 0; s < NSLOT; ++s) tot += partials[(size_t)s * N_ROWS + row];
  float term = (log2f(tot) - pos_buf[row]) * LN2F;
#pragma unroll
  for (int off = 32; off > 0; off >>= 1) term += __shfl_xor(term, off);
  __shared__ float wsum[4];
  if ((threadIdx.x & 63) == 0) wsum[threadIdx.x >> 6] = term;
  __syncthreads();
  if (threadIdx.x == 0)
    loss_part[blockIdx.x] = wsum[0] + wsum[1] + wsum[2] + wsum[3];
}

// ---------------- Kernel 4: final 32 -> 1 ----------------
__global__ __launch_bounds__(64) void reduce2_kernel(
    const float* __restrict__ loss_part, float* __restrict__ out) {
  float v = (threadIdx.x < 32) ? loss_part[threadIdx.x] : 0.f;
#pragma unroll
  for (int off = 32; off > 0; off >>= 1) v += __shfl_xor(v, off);
  if (threadIdx.x == 0) out[0] = v / (float)N_ROWS;
}

extern "C" void kernel_launch(void* const* d_in, const int* in_sizes, int n_in,
                              void* d_out, int out_size, void* d_ws, size_t ws_size,
                              hipStream_t stream) {
  const float* z_i = (const float*)d_in[0];
  const float* z_j = (const float*)d_in[1];
  float* out = (float*)d_out;

  ushort* Zu = (ushort*)d_ws;                                       // 2 MB
  ushort* Zs = Zu + (size_t)N_ROWS * D;                             // 2 MB
  float* partials = (float*)(Zs + (size_t)N_ROWS * D);              // 1 MB
  float* pos_buf = partials + (size_t)NSLOT * N_ROWS;               // 32 KB
  float* loss_part = pos_buf + N_ROWS;                              // small

  hipLaunchKernelGGL(normalize_kernel, dim3(N_ROWS / 4), dim3(256), 0, stream,
                     z_i, z_j, Zu, Zs);
  hipLaunchKernelGGL(sim_kernel, dim3(NBLK), dim3(512), 0, stream, Zu, Zs,
                     partials, pos_buf);
  hipLaunchKernelGGL(reduce1_kernel, dim3(N_ROWS / 256), dim3(256), 0, stream,
                     partials, pos_buf, loss_part);
  hipLaunchKernelGGL(reduce2_kernel, dim3(1), dim3(64), 0, stream, loss_part,
                     out);
}